// Round 1
// baseline (220.562 us; speedup 1.0000x reference)
//
#include <hip/hip_runtime.h>
#include <math.h>

#define D_MODEL 300
#define LSEQ    512
#define NBATCH  300          // only b = d diagonal entries, d < 300
#define SCALE   17.32050807568877f   // sqrt(300)

// pe[l, e]: e even -> sin(l * div[e/2]); e odd -> cos(l * div[e/2])
// div[k] = exp(2k * (-ln(10000)/300))
__global__ void pe_kernel(float* __restrict__ pe) {
    int idx = blockIdx.x * blockDim.x + threadIdx.x;
    if (idx >= LSEQ * D_MODEL) return;
    int l = idx / D_MODEL;
    int e = idx - l * D_MODEL;
    int k = e >> 1;
    float dv = expf((float)(2 * k) * (-9.210340371976184f / 300.0f));
    float arg = (float)l * dv;
    pe[idx] = (e & 1) ? cosf(arg) : sinf(arg);
}

// One block per i (the surviving batch index). D[i*300 + e] = diag[e, i].
__global__ void diag_kernel(const int* __restrict__ x1, const int* __restrict__ x2,
                            const float* __restrict__ emb1, const float* __restrict__ emb2,
                            const float* __restrict__ pe, float* __restrict__ Dm) {
    __shared__ int   x1row[LSEQ];
    __shared__ float s[LSEQ];
    const int i   = blockIdx.x;
    const int tid = threadIdx.x;

    for (int l = tid; l < LSEQ; l += blockDim.x) {
        x1row[l] = x1[i * LSEQ + l];
        int idx2 = x2[i * LSEQ + l];
        s[l] = emb2[idx2 * D_MODEL + i] * SCALE + pe[l * D_MODEL + i];
    }
    __syncthreads();

    if (tid < D_MODEL) {
        float acc = 0.0f;
        #pragma unroll 4
        for (int l = 0; l < LSEQ; ++l) {
            // coalesced: lanes e=0..299 read consecutive floats of one emb1 row
            float e1v = emb1[x1row[l] * D_MODEL + tid] * SCALE + pe[l * D_MODEL + tid];
            acc = fmaf(s[l], e1v, acc);
        }
        Dm[i * D_MODEL + tid] = acc;
    }
}

// H[j*300 + e] = relu( sum_k w1[j,k] * D[k][e] + b1[j] )
// w1 row is block-uniform (scalar loads); D reads coalesced across lanes.
__global__ void fc1_kernel(const float* __restrict__ w1, const float* __restrict__ b1,
                           const float* __restrict__ Dm, float* __restrict__ H) {
    const int j = blockIdx.x;
    const int e = threadIdx.x;
    if (e >= D_MODEL) return;
    const float* w1row = w1 + j * D_MODEL;
    float acc = 0.0f;
    #pragma unroll 4
    for (int k = 0; k < D_MODEL; ++k)
        acc = fmaf(w1row[k], Dm[k * D_MODEL + e], acc);
    H[j * D_MODEL + e] = fmaxf(acc + b1[j], 0.0f);
}

// logits[e, o] = sum_j H[j][e] * w2[o, j] + b2[o]; softmax over o (4)
__global__ void fc2_softmax_kernel(const float* __restrict__ H, const float* __restrict__ w2,
                                   const float* __restrict__ b2, float* __restrict__ out) {
    const int e = blockIdx.x * blockDim.x + threadIdx.x;
    if (e >= D_MODEL) return;
    float a0 = b2[0], a1 = b2[1], a2 = b2[2], a3 = b2[3];
    #pragma unroll 4
    for (int j = 0; j < D_MODEL; ++j) {
        float hv = H[j * D_MODEL + e];   // coalesced across lanes
        a0 = fmaf(hv, w2[0 * D_MODEL + j], a0);
        a1 = fmaf(hv, w2[1 * D_MODEL + j], a1);
        a2 = fmaf(hv, w2[2 * D_MODEL + j], a2);
        a3 = fmaf(hv, w2[3 * D_MODEL + j], a3);
    }
    float m  = fmaxf(fmaxf(a0, a1), fmaxf(a2, a3));
    float x0 = expf(a0 - m), x1 = expf(a1 - m), x2 = expf(a2 - m), x3 = expf(a3 - m);
    float inv = 1.0f / (x0 + x1 + x2 + x3);
    out[e * 4 + 0] = x0 * inv;
    out[e * 4 + 1] = x1 * inv;
    out[e * 4 + 2] = x2 * inv;
    out[e * 4 + 3] = x3 * inv;
}

extern "C" void kernel_launch(void* const* d_in, const int* in_sizes, int n_in,
                              void* d_out, int out_size, void* d_ws, size_t ws_size,
                              hipStream_t stream) {
    const int*   x1   = (const int*)d_in[0];
    const int*   x2   = (const int*)d_in[1];
    const float* emb1 = (const float*)d_in[2];
    const float* emb2 = (const float*)d_in[3];
    const float* w1   = (const float*)d_in[4];
    const float* b1   = (const float*)d_in[5];
    const float* w2   = (const float*)d_in[6];
    const float* b2   = (const float*)d_in[7];
    float* out = (float*)d_out;

    char* ws = (char*)d_ws;
    float* pe = (float*)ws;                         // 512*300*4 = 614400 B
    float* Dm = (float*)(ws + 614400);              // 300*300*4 = 360000 B
    float* H  = (float*)(ws + 614400 + 360000);     // 300*300*4 = 360000 B

    pe_kernel<<<(LSEQ * D_MODEL + 255) / 256, 256, 0, stream>>>(pe);
    diag_kernel<<<NBATCH, 320, 0, stream>>>(x1, x2, emb1, emb2, pe, Dm);
    fc1_kernel<<<D_MODEL, 320, 0, stream>>>(w1, b1, Dm, H);
    fc2_softmax_kernel<<<2, 256, 0, stream>>>(H, w2, b2, out);
}

// Round 2
// 165.494 us; speedup vs baseline: 1.3327x; 1.3327x over previous
//
#include <hip/hip_runtime.h>
#include <math.h>

#define D_MODEL 300
#define LSEQ    512
#define NBATCH  300
#define SPLIT   4
#define LCH     (LSEQ / SPLIT)      // 128
#define KCH     (D_MODEL / SPLIT)   // 75
#define SCALE   17.32050807568877f  // sqrt(300)

// pe[l, e]: e even -> sin(l * div[e/2]); e odd -> cos(l * div[e/2])
__global__ void pe_kernel(float* __restrict__ pe) {
    int idx = blockIdx.x * blockDim.x + threadIdx.x;
    if (idx >= LSEQ * D_MODEL) return;
    int l = idx / D_MODEL;
    int e = idx - l * D_MODEL;
    int k = e >> 1;
    float dv = expf((float)(2 * k) * (-9.210340371976184f / 300.0f));
    float arg = (float)l * dv;
    pe[idx] = (e & 1) ? cosf(arg) : sinf(arg);
}

// S[i][l] = emb2[x2[i,l], i]*scale + pe[l, i]
__global__ void s_kernel(const int* __restrict__ x2, const float* __restrict__ emb2,
                         const float* __restrict__ pe, float* __restrict__ S) {
    const int i = blockIdx.x;
    const int l = threadIdx.x;
    int idx2 = x2[i * LSEQ + l];
    S[i * LSEQ + l] = emb2[idx2 * D_MODEL + i] * SCALE + pe[l * D_MODEL + i];
}

// Gather part: Dm[i][e] += SCALE * sum_{l in chunk} S[i][l] * emb1[x1[i,l]][e]
__global__ void diag_gather_kernel(const int* __restrict__ x1, const float* __restrict__ emb1,
                                   const float* __restrict__ S, float* __restrict__ Dm) {
    __shared__ int   x1ch[LCH];
    __shared__ float sch[LCH];
    const int i   = blockIdx.x;   // batch index
    const int sp  = blockIdx.y;   // l-chunk
    const int tid = threadIdx.x;
    const int l0  = sp * LCH;

    if (tid < LCH) {
        x1ch[tid] = x1[i * LSEQ + l0 + tid];
        sch[tid]  = S[i * LSEQ + l0 + tid];
    }
    __syncthreads();

    if (tid < D_MODEL) {
        float acc = 0.0f;
        #pragma unroll 8
        for (int l = 0; l < LCH; ++l)
            acc = fmaf(sch[l], emb1[x1ch[l] * D_MODEL + tid], acc);
        atomicAdd(&Dm[i * D_MODEL + tid], acc * SCALE);
    }
}

// PE part: Dm[i][e] += sum_{l in chunk} S[i][l] * pe[l][e]
__global__ void diag_pe_kernel(const float* __restrict__ S, const float* __restrict__ pe,
                               float* __restrict__ Dm) {
    __shared__ float sch[LCH];
    const int i   = blockIdx.x;
    const int sp  = blockIdx.y;
    const int tid = threadIdx.x;
    const int l0  = sp * LCH;

    if (tid < LCH) sch[tid] = S[i * LSEQ + l0 + tid];
    __syncthreads();

    if (tid < D_MODEL) {
        float acc = 0.0f;
        #pragma unroll 8
        for (int l = 0; l < LCH; ++l)
            acc = fmaf(sch[l], pe[(l0 + l) * D_MODEL + tid], acc);
        atomicAdd(&Dm[i * D_MODEL + tid], acc);
    }
}

// fc1 k-split partial: Hpre[j][e] += sum_{k in chunk} w1[j,k] * Dm[k][e]
__global__ void fc1_kernel(const float* __restrict__ w1, const float* __restrict__ Dm,
                           float* __restrict__ Hpre) {
    const int j   = blockIdx.x;
    const int sp  = blockIdx.y;
    const int tid = threadIdx.x;
    const int k0  = sp * KCH;
    if (tid >= D_MODEL) return;
    const float* w1row = w1 + j * D_MODEL + k0;
    float acc = 0.0f;
    #pragma unroll 5
    for (int k = 0; k < KCH; ++k)
        acc = fmaf(w1row[k], Dm[(k0 + k) * D_MODEL + tid], acc);
    atomicAdd(&Hpre[j * D_MODEL + tid], acc);
}

// Fused bias + relu + fc2 + softmax. Block = 256 thr = 64 e-lanes x 4 j-chunks.
__global__ void fc2_softmax_kernel(const float* __restrict__ Hpre, const float* __restrict__ b1,
                                   const float* __restrict__ w2, const float* __restrict__ b2,
                                   float* __restrict__ out) {
    __shared__ float sm[4][4][64];   // [jc][o][e_loc]
    const int tid   = threadIdx.x;
    const int e_loc = tid & 63;
    const int jc    = tid >> 6;
    const int e     = blockIdx.x * 64 + e_loc;

    float a0 = 0.f, a1 = 0.f, a2 = 0.f, a3 = 0.f;
    if (e < D_MODEL) {
        const int j0 = jc * KCH;   // 75 j's per chunk
        #pragma unroll 5
        for (int j = j0; j < j0 + KCH; ++j) {
            float h = fmaxf(Hpre[j * D_MODEL + e] + b1[j], 0.0f);
            a0 = fmaf(h, w2[0 * D_MODEL + j], a0);
            a1 = fmaf(h, w2[1 * D_MODEL + j], a1);
            a2 = fmaf(h, w2[2 * D_MODEL + j], a2);
            a3 = fmaf(h, w2[3 * D_MODEL + j], a3);
        }
    }
    sm[jc][0][e_loc] = a0; sm[jc][1][e_loc] = a1;
    sm[jc][2][e_loc] = a2; sm[jc][3][e_loc] = a3;
    __syncthreads();

    if (jc == 0 && e < D_MODEL) {
        float l0 = b2[0] + sm[0][0][e_loc] + sm[1][0][e_loc] + sm[2][0][e_loc] + sm[3][0][e_loc];
        float l1 = b2[1] + sm[0][1][e_loc] + sm[1][1][e_loc] + sm[2][1][e_loc] + sm[3][1][e_loc];
        float l2 = b2[2] + sm[0][2][e_loc] + sm[1][2][e_loc] + sm[2][2][e_loc] + sm[3][2][e_loc];
        float l3 = b2[3] + sm[0][3][e_loc] + sm[1][3][e_loc] + sm[2][3][e_loc] + sm[3][3][e_loc];
        float m  = fmaxf(fmaxf(l0, l1), fmaxf(l2, l3));
        float x0 = expf(l0 - m), x1 = expf(l1 - m), x2 = expf(l2 - m), x3 = expf(l3 - m);
        float inv = 1.0f / (x0 + x1 + x2 + x3);
        out[e * 4 + 0] = x0 * inv;
        out[e * 4 + 1] = x1 * inv;
        out[e * 4 + 2] = x2 * inv;
        out[e * 4 + 3] = x3 * inv;
    }
}

extern "C" void kernel_launch(void* const* d_in, const int* in_sizes, int n_in,
                              void* d_out, int out_size, void* d_ws, size_t ws_size,
                              hipStream_t stream) {
    const int*   x1   = (const int*)d_in[0];
    const int*   x2   = (const int*)d_in[1];
    const float* emb1 = (const float*)d_in[2];
    const float* emb2 = (const float*)d_in[3];
    const float* w1   = (const float*)d_in[4];
    const float* b1   = (const float*)d_in[5];
    const float* w2   = (const float*)d_in[6];
    const float* b2   = (const float*)d_in[7];
    float* out = (float*)d_out;

    char* ws = (char*)d_ws;
    float* pe   = (float*)ws;                         // 512*300*4 = 614400 B
    float* S    = (float*)(ws + 614400);              // 300*512*4 = 614400 B
    float* Dm   = (float*)(ws + 1228800);             // 300*300*4 = 360000 B
    float* Hpre = (float*)(ws + 1228800 + 360000);    // 300*300*4 = 360000 B

    // zero the two atomic-accumulated buffers (contiguous)
    hipMemsetAsync(Dm, 0, 2 * 360000, stream);

    pe_kernel<<<(LSEQ * D_MODEL + 255) / 256, 256, 0, stream>>>(pe);
    s_kernel<<<NBATCH, LSEQ, 0, stream>>>(x2, emb2, pe, S);
    diag_gather_kernel<<<dim3(NBATCH, SPLIT), 320, 0, stream>>>(x1, emb1, S, Dm);
    diag_pe_kernel<<<dim3(NBATCH, SPLIT), 320, 0, stream>>>(S, pe, Dm);
    fc1_kernel<<<dim3(D_MODEL, SPLIT), 320, 0, stream>>>(w1, Dm, Hpre);
    fc2_softmax_kernel<<<(D_MODEL + 63) / 64, 256, 0, stream>>>(Hpre, b1, w2, b2, out);
}

// Round 4
// 160.198 us; speedup vs baseline: 1.3768x; 1.0331x over previous
//
#include <hip/hip_runtime.h>
#include <math.h>

#define D_MODEL 300
#define LSEQ    512
#define NBATCH  300
#define SPLIT   4
#define LCH     (LSEQ / SPLIT)      // 128
#define KCH     (D_MODEL / SPLIT)   // 75
#define JPB     2                   // j-rows per fc1 block
#define SCALE   17.32050807568877f  // sqrt(300)

// pe[l, e]: e even -> sin(l * div[e/2]); e odd -> cos(l * div[e/2])
__global__ void pe_kernel(float* __restrict__ pe) {
    int idx = blockIdx.x * blockDim.x + threadIdx.x;
    if (idx >= LSEQ * D_MODEL) return;
    int l = idx / D_MODEL;
    int e = idx - l * D_MODEL;
    int k = e >> 1;
    float dv = expf((float)(2 * k) * (-9.210340371976184f / 300.0f));
    float arg = (float)l * dv;
    pe[idx] = (e & 1) ? cosf(arg) : sinf(arg);
}

// Fused: computes s-chunk inline (emb2 gather + pe), then
// Dm[i][e] += sum_{l in chunk} s[l] * (SCALE*emb1[x1[i,l]][e] + pe[l][e])
__global__ void diag_fused_kernel(const int* __restrict__ x1, const int* __restrict__ x2,
                                  const float* __restrict__ emb1, const float* __restrict__ emb2,
                                  const float* __restrict__ pe, float* __restrict__ Dm) {
    __shared__ int   x1ch[LCH];
    __shared__ float sch[LCH];
    const int i   = blockIdx.x;   // batch index (== diagonal index)
    const int sp  = blockIdx.y;   // l-chunk
    const int tid = threadIdx.x;
    const int l0  = sp * LCH;

    if (tid < LCH) {
        const int l = l0 + tid;
        x1ch[tid] = x1[i * LSEQ + l];
        int idx2  = x2[i * LSEQ + l];
        sch[tid]  = emb2[idx2 * D_MODEL + i] * SCALE + pe[l * D_MODEL + i];
    }
    __syncthreads();

    if (tid < D_MODEL) {
        float acc = 0.0f;
        #pragma unroll 8
        for (int l = 0; l < LCH; ++l) {
            // e1 value incl. positional term; both loads coalesced across lanes
            float e1v = fmaf(emb1[x1ch[l] * D_MODEL + tid], SCALE,
                             pe[(l0 + l) * D_MODEL + tid]);
            acc = fmaf(sch[l], e1v, acc);
        }
        atomicAdd(&Dm[i * D_MODEL + tid], acc);
    }
}

// fc1 k-split partial, JPB j-rows per block for Dm reuse:
// Hpre[j][e] += sum_{k in chunk} w1[j,k] * Dm[k][e]
__global__ void fc1_kernel(const float* __restrict__ w1, const float* __restrict__ Dm,
                           float* __restrict__ Hpre) {
    const int j0  = blockIdx.x * JPB;
    const int sp  = blockIdx.y;
    const int tid = threadIdx.x;
    const int k0  = sp * KCH;
    if (tid >= D_MODEL) return;
    const float* w1r0 = w1 + (j0 + 0) * D_MODEL + k0;
    const float* w1r1 = w1 + (j0 + 1) * D_MODEL + k0;
    float acc0 = 0.0f, acc1 = 0.0f;
    #pragma unroll 5
    for (int k = 0; k < KCH; ++k) {
        float d = Dm[(k0 + k) * D_MODEL + tid];
        acc0 = fmaf(w1r0[k], d, acc0);
        acc1 = fmaf(w1r1[k], d, acc1);
    }
    atomicAdd(&Hpre[(j0 + 0) * D_MODEL + tid], acc0);
    atomicAdd(&Hpre[(j0 + 1) * D_MODEL + tid], acc1);
}

// Fused bias + relu + fc2 + softmax. Block = 256 thr = 64 e-lanes x 4 j-chunks.
__global__ void fc2_softmax_kernel(const float* __restrict__ Hpre, const float* __restrict__ b1,
                                   const float* __restrict__ w2, const float* __restrict__ b2,
                                   float* __restrict__ out) {
    __shared__ float sm[4][4][64];   // [jc][o][e_loc]
    const int tid   = threadIdx.x;
    const int e_loc = tid & 63;
    const int jc    = tid >> 6;
    const int e     = blockIdx.x * 64 + e_loc;

    float a0 = 0.f, a1 = 0.f, a2 = 0.f, a3 = 0.f;
    if (e < D_MODEL) {
        const int j0 = jc * KCH;   // 75 j's per chunk
        #pragma unroll 5
        for (int j = j0; j < j0 + KCH; ++j) {
            float h = fmaxf(Hpre[j * D_MODEL + e] + b1[j], 0.0f);
            a0 = fmaf(h, w2[0 * D_MODEL + j], a0);
            a1 = fmaf(h, w2[1 * D_MODEL + j], a1);
            a2 = fmaf(h, w2[2 * D_MODEL + j], a2);
            a3 = fmaf(h, w2[3 * D_MODEL + j], a3);
        }
    }
    sm[jc][0][e_loc] = a0; sm[jc][1][e_loc] = a1;
    sm[jc][2][e_loc] = a2; sm[jc][3][e_loc] = a3;
    __syncthreads();

    if (jc == 0 && e < D_MODEL) {
        float l0 = b2[0] + sm[0][0][e_loc] + sm[1][0][e_loc] + sm[2][0][e_loc] + sm[3][0][e_loc];
        float l1 = b2[1] + sm[0][1][e_loc] + sm[1][1][e_loc] + sm[2][1][e_loc] + sm[3][1][e_loc];
        float l2 = b2[2] + sm[0][2][e_loc] + sm[1][2][e_loc] + sm[2][2][e_loc] + sm[3][2][e_loc];
        float l3 = b2[3] + sm[0][3][e_loc] + sm[1][3][e_loc] + sm[2][3][e_loc] + sm[3][3][e_loc];
        float m  = fmaxf(fmaxf(l0, l1), fmaxf(l2, l3));
        float x0 = expf(l0 - m), x1 = expf(l1 - m), x2 = expf(l2 - m), x3 = expf(l3 - m);
        float inv = 1.0f / (x0 + x1 + x2 + x3);
        out[e * 4 + 0] = x0 * inv;
        out[e * 4 + 1] = x1 * inv;
        out[e * 4 + 2] = x2 * inv;
        out[e * 4 + 3] = x3 * inv;
    }
}

extern "C" void kernel_launch(void* const* d_in, const int* in_sizes, int n_in,
                              void* d_out, int out_size, void* d_ws, size_t ws_size,
                              hipStream_t stream) {
    const int*   x1   = (const int*)d_in[0];
    const int*   x2   = (const int*)d_in[1];
    const float* emb1 = (const float*)d_in[2];
    const float* emb2 = (const float*)d_in[3];
    const float* w1   = (const float*)d_in[4];
    const float* b1   = (const float*)d_in[5];
    const float* w2   = (const float*)d_in[6];
    const float* b2   = (const float*)d_in[7];
    float* out = (float*)d_out;

    char* ws = (char*)d_ws;
    float* pe   = (float*)ws;                 // 512*300*4 = 614400 B
    float* Dm   = (float*)(ws + 614400);      // 300*300*4 = 360000 B
    float* Hpre = (float*)(ws + 974400);      // 300*300*4 = 360000 B

    // zero the two atomic-accumulated buffers (contiguous)
    (void)hipMemsetAsync(Dm, 0, 2 * 360000, stream);

    pe_kernel<<<(LSEQ * D_MODEL + 255) / 256, 256, 0, stream>>>(pe);
    diag_fused_kernel<<<dim3(NBATCH, SPLIT), 320, 0, stream>>>(x1, x2, emb1, emb2, pe, Dm);
    fc1_kernel<<<dim3(D_MODEL / JPB, SPLIT), 320, 0, stream>>>(w1, Dm, Hpre);
    fc2_softmax_kernel<<<(D_MODEL + 63) / 64, 256, 0, stream>>>(Hpre, b1, w2, b2, out);
}

// Round 5
// 157.865 us; speedup vs baseline: 1.3972x; 1.0148x over previous
//
#include <hip/hip_runtime.h>
#include <math.h>

#define D_MODEL 300
#define LSEQ    512
#define NBATCH  300
#define SPLIT   8
#define LCH     (LSEQ / SPLIT)      // 64 l-values per block
#define NG      4                   // parallel l-streams (groups) per block
#define NR      75                  // float4 lanes per row (75*4 = 300)
#define KCH     (D_MODEL / 4)       // 75, fc1 k-chunk
#define JPB     2                   // j-rows per fc1 block
#define SCALE   17.32050807568877f  // sqrt(300)

// pe[l, e]: e even -> sin(l * div[e/2]); e odd -> cos(l * div[e/2])
__global__ void pe_kernel(float* __restrict__ pe) {
    int idx = blockIdx.x * blockDim.x + threadIdx.x;
    if (idx >= LSEQ * D_MODEL) return;
    int l = idx / D_MODEL;
    int e = idx - l * D_MODEL;
    int k = e >> 1;
    float dv = expf((float)(2 * k) * (-9.210340371976184f / 300.0f));
    float arg = (float)l * dv;
    pe[idx] = (e & 1) ? cosf(arg) : sinf(arg);
}

// Dm[i][e] += sum_{l in chunk} s[l] * (SCALE*emb1[x1[i,l]][e] + pe[l][e])
// float4-vectorized gather; 4 l-streams of 75 lanes each; LDS reduce.
__global__ void diag_fused_kernel(const int* __restrict__ x1, const int* __restrict__ x2,
                                  const float* __restrict__ emb1, const float* __restrict__ emb2,
                                  const float* __restrict__ pe, float* __restrict__ Dm) {
    __shared__ int    x1ch[LCH];
    __shared__ float  sch[LCH];
    __shared__ float4 part[NG][NR];
    const int i   = blockIdx.x;   // batch index (== diagonal index)
    const int sp  = blockIdx.y;   // l-chunk
    const int tid = threadIdx.x;
    const int l0  = sp * LCH;

    if (tid < LCH) {
        const int l = l0 + tid;
        x1ch[tid] = x1[i * LSEQ + l];
        int idx2  = x2[i * LSEQ + l];
        sch[tid]  = emb2[idx2 * D_MODEL + i] * SCALE + pe[l * D_MODEL + i];
    }
    __syncthreads();

    const int g = tid / NR;       // l-stream
    const int r = tid - g * NR;   // float4 index within row

    if (tid < NG * NR) {
        float ax = 0.f, ay = 0.f, az = 0.f, aw = 0.f;
        #pragma unroll 4
        for (int l = g; l < LCH; l += NG) {
            const float4 ev = ((const float4*)(emb1 + (size_t)x1ch[l] * D_MODEL))[r];
            const float4 pv = ((const float4*)(pe   + (size_t)(l0 + l) * D_MODEL))[r];
            const float  s  = sch[l];
            ax = fmaf(s, fmaf(ev.x, SCALE, pv.x), ax);
            ay = fmaf(s, fmaf(ev.y, SCALE, pv.y), ay);
            az = fmaf(s, fmaf(ev.z, SCALE, pv.z), az);
            aw = fmaf(s, fmaf(ev.w, SCALE, pv.w), aw);
        }
        part[g][r] = make_float4(ax, ay, az, aw);
    }
    __syncthreads();

    if (g == 0 && tid < NR) {
        float4 p0 = part[0][r], p1 = part[1][r], p2 = part[2][r], p3 = part[3][r];
        float* dst = Dm + i * D_MODEL + 4 * r;
        atomicAdd(dst + 0, p0.x + p1.x + p2.x + p3.x);
        atomicAdd(dst + 1, p0.y + p1.y + p2.y + p3.y);
        atomicAdd(dst + 2, p0.z + p1.z + p2.z + p3.z);
        atomicAdd(dst + 3, p0.w + p1.w + p2.w + p3.w);
    }
}

// fc1 k-split partial, JPB j-rows per block for Dm reuse:
// Hpre[j][e] += sum_{k in chunk} w1[j,k] * Dm[k][e]
__global__ void fc1_kernel(const float* __restrict__ w1, const float* __restrict__ Dm,
                           float* __restrict__ Hpre) {
    const int j0  = blockIdx.x * JPB;
    const int sp  = blockIdx.y;
    const int tid = threadIdx.x;
    const int k0  = sp * KCH;
    if (tid >= D_MODEL) return;
    const float* w1r0 = w1 + (j0 + 0) * D_MODEL + k0;
    const float* w1r1 = w1 + (j0 + 1) * D_MODEL + k0;
    float acc0 = 0.0f, acc1 = 0.0f;
    #pragma unroll 5
    for (int k = 0; k < KCH; ++k) {
        float d = Dm[(k0 + k) * D_MODEL + tid];
        acc0 = fmaf(w1r0[k], d, acc0);
        acc1 = fmaf(w1r1[k], d, acc1);
    }
    atomicAdd(&Hpre[(j0 + 0) * D_MODEL + tid], acc0);
    atomicAdd(&Hpre[(j0 + 1) * D_MODEL + tid], acc1);
}

// Fused bias + relu + fc2 + softmax. Block = 256 thr = 64 e-lanes x 4 j-chunks.
__global__ void fc2_softmax_kernel(const float* __restrict__ Hpre, const float* __restrict__ b1,
                                   const float* __restrict__ w2, const float* __restrict__ b2,
                                   float* __restrict__ out) {
    __shared__ float sm[4][4][64];   // [jc][o][e_loc]
    const int tid   = threadIdx.x;
    const int e_loc = tid & 63;
    const int jc    = tid >> 6;
    const int e     = blockIdx.x * 64 + e_loc;

    float a0 = 0.f, a1 = 0.f, a2 = 0.f, a3 = 0.f;
    if (e < D_MODEL) {
        const int j0 = jc * 75;
        #pragma unroll 5
        for (int j = j0; j < j0 + 75; ++j) {
            float h = fmaxf(Hpre[j * D_MODEL + e] + b1[j], 0.0f);
            a0 = fmaf(h, w2[0 * D_MODEL + j], a0);
            a1 = fmaf(h, w2[1 * D_MODEL + j], a1);
            a2 = fmaf(h, w2[2 * D_MODEL + j], a2);
            a3 = fmaf(h, w2[3 * D_MODEL + j], a3);
        }
    }
    sm[jc][0][e_loc] = a0; sm[jc][1][e_loc] = a1;
    sm[jc][2][e_loc] = a2; sm[jc][3][e_loc] = a3;
    __syncthreads();

    if (jc == 0 && e < D_MODEL) {
        float l0 = b2[0] + sm[0][0][e_loc] + sm[1][0][e_loc] + sm[2][0][e_loc] + sm[3][0][e_loc];
        float l1 = b2[1] + sm[0][1][e_loc] + sm[1][1][e_loc] + sm[2][1][e_loc] + sm[3][1][e_loc];
        float l2 = b2[2] + sm[0][2][e_loc] + sm[1][2][e_loc] + sm[2][2][e_loc] + sm[3][2][e_loc];
        float l3 = b2[3] + sm[0][3][e_loc] + sm[1][3][e_loc] + sm[2][3][e_loc] + sm[3][3][e_loc];
        float m  = fmaxf(fmaxf(l0, l1), fmaxf(l2, l3));
        float x0 = expf(l0 - m), x1 = expf(l1 - m), x2 = expf(l2 - m), x3 = expf(l3 - m);
        float inv = 1.0f / (x0 + x1 + x2 + x3);
        out[e * 4 + 0] = x0 * inv;
        out[e * 4 + 1] = x1 * inv;
        out[e * 4 + 2] = x2 * inv;
        out[e * 4 + 3] = x3 * inv;
    }
}

extern "C" void kernel_launch(void* const* d_in, const int* in_sizes, int n_in,
                              void* d_out, int out_size, void* d_ws, size_t ws_size,
                              hipStream_t stream) {
    const int*   x1   = (const int*)d_in[0];
    const int*   x2   = (const int*)d_in[1];
    const float* emb1 = (const float*)d_in[2];
    const float* emb2 = (const float*)d_in[3];
    const float* w1   = (const float*)d_in[4];
    const float* b1   = (const float*)d_in[5];
    const float* w2   = (const float*)d_in[6];
    const float* b2   = (const float*)d_in[7];
    float* out = (float*)d_out;

    char* ws = (char*)d_ws;
    float* pe   = (float*)ws;                 // 512*300*4 = 614400 B
    float* Dm   = (float*)(ws + 614400);      // 300*300*4 = 360000 B
    float* Hpre = (float*)(ws + 974400);      // 300*300*4 = 360000 B

    // zero the two atomic-accumulated buffers (contiguous)
    (void)hipMemsetAsync(Dm, 0, 2 * 360000, stream);

    pe_kernel<<<(LSEQ * D_MODEL + 255) / 256, 256, 0, stream>>>(pe);
    diag_fused_kernel<<<dim3(NBATCH, SPLIT), 320, 0, stream>>>(x1, x2, emb1, emb2, pe, Dm);
    fc1_kernel<<<dim3(D_MODEL / JPB, 4), 320, 0, stream>>>(w1, Dm, Hpre);
    fc2_softmax_kernel<<<(D_MODEL + 63) / 64, 256, 0, stream>>>(Hpre, b1, w2, b2, out);
}